// Round 2
// baseline (184.849 us; speedup 1.0000x reference)
//
#include <hip/hip_runtime.h>
#include <math.h>

typedef __attribute__((ext_vector_type(8))) short bf16x8;
typedef __attribute__((ext_vector_type(4))) float f32x4;
typedef unsigned short ushort_t;

static __device__ inline unsigned short f2bf(float f) {
    union { float f; unsigned u; } v; v.f = f;
    unsigned r = v.u + 0x7fff + ((v.u >> 16) & 1);
    return (unsigned short)(r >> 16);
}

#if defined(__has_builtin)
#  if __has_builtin(__builtin_amdgcn_cvt_pk_bf16_f32)
#    define HAVE_PK_BF16 1
#  endif
#endif

static __device__ inline unsigned pk2bf(float a, float b) {
#ifdef HAVE_PK_BF16
    auto r = __builtin_amdgcn_cvt_pk_bf16_f32(a, b);
    unsigned u; __builtin_memcpy(&u, &r, 4);
    return u;
#else
    return (unsigned)f2bf(a) | ((unsigned)f2bf(b) << 16);
#endif
}

// ---------------------------------------------------------------------------
// fp32 -> bf16 pre-convert (row_emb, col_emb, Wq, Wk, Wv, Wout) -> ws bf16.
// ---------------------------------------------------------------------------
__global__ __launch_bounds__(256) void convert_all(const float* __restrict__ a0,
                                                   const float* __restrict__ a1,
                                                   const float* __restrict__ a2,
                                                   const float* __restrict__ a3,
                                                   const float* __restrict__ a4,
                                                   const float* __restrict__ a5,
                                                   ushort_t* __restrict__ dst) {
    const size_t e = ((size_t)blockIdx.x * 256 + threadIdx.x) * 4;
    const float* src; size_t off;
    if      (e < 1048576) { src = a0; off = 0; }
    else if (e < 2097152) { src = a1; off = 1048576; }
    else if (e < 2359296) { src = a2; off = 2097152; }
    else if (e < 2621440) { src = a3; off = 2359296; }
    else if (e < 2883584) { src = a4; off = 2621440; }
    else                  { src = a5; off = 2883584; }
    const float4 v = *(const float4*)(src + (e - off));
    uint2 o; o.x = pk2bf(v.x, v.y); o.y = pk2bf(v.z, v.w);
    *(uint2*)(dst + e) = o;
}

// ---------------------------------------------------------------------------
// Q/K/V projections in one launch. z=0: Q=rowb@Wq^T (bf16 rows out);
// z=1: K=colb@Wk^T; z=2: V=colb@Wv^T stored transposed Vt[bh][d][c].
// ---------------------------------------------------------------------------
__global__ __launch_bounds__(256) void gemm_qkv(const ushort_t* __restrict__ rowb,
                                                const ushort_t* __restrict__ colb,
                                                const ushort_t* __restrict__ Wqb,
                                                const ushort_t* __restrict__ Wkb,
                                                const ushort_t* __restrict__ Wvb,
                                                ushort_t* __restrict__ Qb,
                                                ushort_t* __restrict__ Kb,
                                                ushort_t* __restrict__ Vt) {
    const int z = blockIdx.z;
    const ushort_t* A = (z == 0) ? rowb : colb;
    const ushort_t* B = (z == 0) ? Wqb : (z == 1) ? Wkb : Wvb;

    const int t    = threadIdx.x;
    const int w    = t >> 6;
    const int lane = t & 63;
    const int quad = lane >> 4;
    const int sl   = lane & 15;
    const int m0 = blockIdx.x * 64 + (w >> 1) * 32;
    const int n0 = blockIdx.y * 64 + (w & 1) * 32;

    f32x4 acc[2][2] = {};

    for (int k0 = 0; k0 < 512; k0 += 32) {
        bf16x8 a[2], b[2];
#pragma unroll
        for (int rs = 0; rs < 2; ++rs)
            a[rs] = *(const bf16x8*)(A + (size_t)(m0 + rs * 16 + sl) * 512 + k0 + quad * 8);
#pragma unroll
        for (int cs = 0; cs < 2; ++cs)
            b[cs] = *(const bf16x8*)(B + (size_t)(n0 + cs * 16 + sl) * 512 + k0 + quad * 8);
#pragma unroll
        for (int rs = 0; rs < 2; ++rs)
#pragma unroll
            for (int cs = 0; cs < 2; ++cs)
                acc[rs][cs] = __builtin_amdgcn_mfma_f32_16x16x32_bf16(a[rs], b[cs], acc[rs][cs], 0, 0, 0);
    }

#pragma unroll
    for (int rs = 0; rs < 2; ++rs)
#pragma unroll
        for (int cs = 0; cs < 2; ++cs) {
            const int n = n0 + cs * 16 + sl;
            if (z == 2) {
                const int mb   = m0 + rs * 16 + quad * 4;
                const int bidx = mb >> 9, c = mb & 511;
                const int h = n >> 6, d = n & 63;
                ushort4 o;
                o.x = f2bf(acc[rs][cs][0]); o.y = f2bf(acc[rs][cs][1]);
                o.z = f2bf(acc[rs][cs][2]); o.w = f2bf(acc[rs][cs][3]);
                *(ushort4*)(Vt + (size_t)(((bidx * 8 + h) * 64 + d)) * 512 + c) = o;
            } else {
                ushort_t* C = (z == 0) ? Qb : Kb;
#pragma unroll
                for (int reg = 0; reg < 4; ++reg) {
                    const int m = m0 + rs * 16 + quad * 4 + reg;
                    C[(size_t)m * 512 + n] = f2bf(acc[rs][cs][reg]);
                }
            }
        }
}

// ---------------------------------------------------------------------------
// Final GEMM: out[M][512] = Aoutb @ Woutb^T, fp32 out.
// ---------------------------------------------------------------------------
__global__ __launch_bounds__(256) void gemm_out(const ushort_t* __restrict__ A,
                                                const ushort_t* __restrict__ B,
                                                float* __restrict__ C) {
    const int t    = threadIdx.x;
    const int w    = t >> 6;
    const int lane = t & 63;
    const int quad = lane >> 4;
    const int sl   = lane & 15;
    const int m0 = blockIdx.x * 64 + (w >> 1) * 32;
    const int n0 = blockIdx.y * 64 + (w & 1) * 32;

    f32x4 acc[2][2] = {};

    for (int k0 = 0; k0 < 512; k0 += 32) {
        bf16x8 a[2], b[2];
#pragma unroll
        for (int rs = 0; rs < 2; ++rs)
            a[rs] = *(const bf16x8*)(A + (size_t)(m0 + rs * 16 + sl) * 512 + k0 + quad * 8);
#pragma unroll
        for (int cs = 0; cs < 2; ++cs)
            b[cs] = *(const bf16x8*)(B + (size_t)(n0 + cs * 16 + sl) * 512 + k0 + quad * 8);
#pragma unroll
        for (int rs = 0; rs < 2; ++rs)
#pragma unroll
            for (int cs = 0; cs < 2; ++cs)
                acc[rs][cs] = __builtin_amdgcn_mfma_f32_16x16x32_bf16(a[rs], b[cs], acc[rs][cs], 0, 0, 0);
    }

#pragma unroll
    for (int rs = 0; rs < 2; ++rs)
#pragma unroll
        for (int cs = 0; cs < 2; ++cs) {
            const int n = n0 + cs * 16 + sl;
#pragma unroll
            for (int reg = 0; reg < 4; ++reg) {
                const int m = m0 + rs * 16 + quad * 4 + reg;
                C[(size_t)m * 512 + n] = acc[rs][cs][reg];
            }
        }
}

// ---------------------------------------------------------------------------
// dot + mixing MLP v6: 256 threads (4 waves), 32x16 tile, grid (32,16,4).
// Occupancy-first: LDS 26.6 KB -> up to 6 blocks/CU (was 52 KB / 512 thr).
// Phase A: wave (rs = w>>1, hbj = w&1) computes heads hbj*4..hbj*4+3 for its
//   16-row half x all 16 cols; packs 4 heads per cell into one b64 Xs store.
// Phase B: swapped-operand in-register MLP (as v5), per wave 8 m-tiles of 16
//   cells; Xs row stride 20 shorts keeps slot layout: heads 0..7, cost 8,
//   zeros 9..15 (b64-aligned).
// ---------------------------------------------------------------------------
__global__ __launch_bounds__(256) void dot_mlp_v6(const ushort_t* __restrict__ Qb,
                                                  const ushort_t* __restrict__ Kb,
                                                  const float* __restrict__ cost,
                                                  const float* __restrict__ W1,
                                                  const float* __restrict__ W2,
                                                  float* __restrict__ logits) {
    __shared__ ushort_t Xs[512 * 20];       // 20 KB, row stride 20 shorts
    __shared__ ushort_t W1fs[128 * 16];     // 4 KB
    __shared__ ushort_t W2ss[8 * 128];      // 2 KB

    const int b  = blockIdx.z;
    const int r0 = blockIdx.y * 32;
    const int c0 = blockIdx.x * 16;
    const int t    = threadIdx.x;
    const int w    = t >> 6;
    const int lane = t & 63;
    const int quad = lane >> 4;
    const int sl   = lane & 15;

    const bf16x8 zf = {0, 0, 0, 0, 0, 0, 0, 0};

    // --- stage weights ---
    if (t < 128) {
        float s = 0.f;
#pragma unroll
        for (int h = 0; h < 8; ++h) {
            W1fs[t * 16 + h] = f2bf(W1[t * 16 + 2 * h]);
            s += W1[t * 16 + 2 * h + 1];
        }
        W1fs[t * 16 + 8] = f2bf(s);
#pragma unroll
        for (int k = 9; k < 16; ++k) W1fs[t * 16 + k] = 0;
    }
#pragma unroll
    for (int i = 0; i < 4; ++i) W2ss[t + i * 256] = f2bf(W2[t + i * 256]);

    // --- cost -> X slot 8 (dword 4); zero dwords 5..7 ---
#pragma unroll
    for (int i = 0; i < 2; ++i) {
        const int cell = t + i * 256;
        const int rl = cell >> 4, cl = cell & 15;
        unsigned* base = (unsigned*)(Xs + cell * 20) + 4;
        base[0] = (unsigned)f2bf(cost[((size_t)b * 512 + r0 + rl) * 512 + c0 + cl]);
        base[1] = 0; base[2] = 0; base[3] = 0;
    }

    // --- Phase A: wave = (row-half rs, head-quad hbj) ---
    {
        const int rs  = w >> 1;
        const int hbj = w & 1;
        unsigned uu[2][4];
#pragma unroll
        for (int hp = 0; hp < 2; ++hp) {
            const int h0 = hbj * 4 + hp * 2;
            bf16x8 qa[2][2], ka[2][2];
#pragma unroll
            for (int hh = 0; hh < 2; ++hh)
#pragma unroll
                for (int ks = 0; ks < 2; ++ks) {
                    qa[hh][ks] = *(const bf16x8*)(Qb +
                        ((size_t)(b * 512 + r0 + rs * 16 + sl) * 512 + (h0 + hh) * 64 + ks * 32 + quad * 8));
                    ka[hh][ks] = *(const bf16x8*)(Kb +
                        ((size_t)(b * 512 + c0 + sl) * 512 + (h0 + hh) * 64 + ks * 32 + quad * 8));
                }
            f32x4 ac0 = {0.f, 0.f, 0.f, 0.f}, ac1 = {0.f, 0.f, 0.f, 0.f};
            ac0 = __builtin_amdgcn_mfma_f32_16x16x32_bf16(qa[0][0], ka[0][0], ac0, 0, 0, 0);
            ac0 = __builtin_amdgcn_mfma_f32_16x16x32_bf16(qa[0][1], ka[0][1], ac0, 0, 0, 0);
            ac1 = __builtin_amdgcn_mfma_f32_16x16x32_bf16(qa[1][0], ka[1][0], ac1, 0, 0, 0);
            ac1 = __builtin_amdgcn_mfma_f32_16x16x32_bf16(qa[1][1], ka[1][1], ac1, 0, 0, 0);
#pragma unroll
            for (int reg = 0; reg < 4; ++reg)
                uu[hp][reg] = pk2bf(ac0[reg] * 0.125f, ac1[reg] * 0.125f);
        }
        const int rowb = rs * 16 + quad * 4;
#pragma unroll
        for (int reg = 0; reg < 4; ++reg) {
            const int cell = (rowb + reg) * 16 + sl;
            unsigned* xp = (unsigned*)(Xs + cell * 20) + hbj * 2;
            xp[0] = uu[0][reg];   // heads hbj*4+0, hbj*4+1
            xp[1] = uu[1][reg];   // heads hbj*4+2, hbj*4+3
        }
    }

    __syncthreads();

    // --- Phase B ---
    // W1 A-frags: lane holds W1row = nt*16+sl, k = quad*8+i (k>=16 zero-padded).
    bf16x8 aw1[8];
#pragma unroll
    for (int nt = 0; nt < 8; ++nt)
        aw1[nt] = (quad < 2) ? *(const bf16x8*)&W1fs[(nt * 16 + sl) * 16 + quad * 8] : zf;

    // W2 A-frags with k permuted to match the hidT pack layout:
    // frag ks, elem i  <->  hidden j = (2ks + (i>>2))*16 + quad*4 + (i&3)
    bf16x8 w2f[4];
#pragma unroll
    for (int ks = 0; ks < 4; ++ks) {
        union { ushort_t s[8]; bf16x8 v; } tu;
#pragma unroll
        for (int i = 0; i < 8; ++i) {
            const int j = (2 * ks + (i >> 2)) * 16 + quad * 4 + (i & 3);
            tu.s[i] = (sl < 8) ? W2ss[sl * 128 + j] : (ushort_t)0;
        }
        w2f[ks] = tu.v;
    }

#pragma unroll
    for (int mt = 0; mt < 8; ++mt) {
        const int gmt  = w * 8 + mt;       // row within tile, 0..31
        const int cell = gmt * 16 + sl;

        // X B-frag: lane holds cell, k = quad*8+i (k>=16 zero-padded).
        bf16x8 a1 = zf;
        if (quad < 2) {
            const unsigned* xr = (const unsigned*)Xs + (size_t)cell * 10 + quad * 4;
            union { unsigned u[4]; bf16x8 v; } tmp;
            tmp.u[0] = xr[0]; tmp.u[1] = xr[1]; tmp.u[2] = xr[2]; tmp.u[3] = xr[3];
            a1 = tmp.v;
        }

        // layer 1: hidT -> lane holds hid units (quad*4+reg) for cell = sl.
        f32x4 acc2 = {0.f, 0.f, 0.f, 0.f};
#pragma unroll
        for (int ks = 0; ks < 4; ++ks) {
            f32x4 z = {0.f, 0.f, 0.f, 0.f};
            const f32x4 h0v = __builtin_amdgcn_mfma_f32_16x16x32_bf16(aw1[2 * ks],     a1, z, 0, 0, 0);
            const f32x4 h1v = __builtin_amdgcn_mfma_f32_16x16x32_bf16(aw1[2 * ks + 1], a1, z, 0, 0, 0);
            union { unsigned u[4]; bf16x8 v; } hb;
            hb.u[0] = pk2bf(fmaxf(h0v[0], 0.f), fmaxf(h0v[1], 0.f));
            hb.u[1] = pk2bf(fmaxf(h0v[2], 0.f), fmaxf(h0v[3], 0.f));
            hb.u[2] = pk2bf(fmaxf(h1v[0], 0.f), fmaxf(h1v[1], 0.f));
            hb.u[3] = pk2bf(fmaxf(h1v[2], 0.f), fmaxf(h1v[3], 0.f));
            acc2 = __builtin_amdgcn_mfma_f32_16x16x32_bf16(w2f[ks], hb.v, acc2, 0, 0, 0);
        }

        // msT: row (quad*4+reg) = head (valid quad<2), col (sl) = cell.
        if (quad < 2) {
            const int r = r0 + gmt;
            const int c = c0 + sl;
#pragma unroll
            for (int reg = 0; reg < 4; ++reg) {
                const int h = quad * 4 + reg;
                logits[((size_t)(b * 8 + h) * 512 + r) * 512 + c] = acc2[reg];
            }
        }
    }
}

// ---------------------------------------------------------------------------
// Fused masked-softmax + PV. grid (16 r-tiles, 32 bh), 256 threads (4 waves).
// Ps row stride 522 shorts (odd dword stride 261) -> ~2-way bank conflicts.
// ---------------------------------------------------------------------------
__global__ __launch_bounds__(256) void softmax_pv(const float* __restrict__ logits,
                                                  const int* __restrict__ mask,
                                                  const ushort_t* __restrict__ Vt,
                                                  ushort_t* __restrict__ Aout) {
    __shared__ ushort_t Ps[32 * 522];   // 33.4 KB

    const int t    = threadIdx.x;
    const int w    = t >> 6;
    const int lane = t & 63;
    const int quad = lane >> 4;
    const int sl   = lane & 15;
    const int rt = blockIdx.x;
    const int bh = blockIdx.y;
    const int r0 = rt * 32;

    // --- softmax: 8 rows per wave, vectorized float4/int4 loads ---
#pragma unroll
    for (int rr = 0; rr < 8; ++rr) {
        const int row = w * 8 + rr;
        const float* lp = logits + ((size_t)bh * 512 + r0 + row) * 512;
        const int*   mp = mask   + ((size_t)bh * 512 + r0 + row) * 512;

        const float4 f0 = ((const float4*)lp)[lane];
        const float4 f1 = ((const float4*)lp)[lane + 64];
        const int4   m0 = ((const int4*)mp)[lane];
        const int4   m1 = ((const int4*)mp)[lane + 64];

        float v[8]; int m[8];
        v[0] = f0.x; v[1] = f0.y; v[2] = f0.z; v[3] = f0.w;
        v[4] = f1.x; v[5] = f1.y; v[6] = f1.z; v[7] = f1.w;
        m[0] = m0.x; m[1] = m0.y; m[2] = m0.z; m[3] = m0.w;
        m[4] = m1.x; m[5] = m1.y; m[6] = m1.z; m[7] = m1.w;

        int allm = 1;
#pragma unroll
        for (int i = 0; i < 8; ++i) allm &= (m[i] != 0);
        const bool all_masked = (__all(allm) != 0);

        float mx = -__builtin_inff();
#pragma unroll
        for (int i = 0; i < 8; ++i) {
            const bool keep = all_masked || (m[i] == 0);
            if (keep) mx = fmaxf(mx, v[i]);
        }
#pragma unroll
        for (int s = 32; s > 0; s >>= 1) mx = fmaxf(mx, __shfl_xor(mx, s, 64));

        float e[8]; float sum = 0.f;
#pragma unroll
        for (int i = 0; i < 8; ++i) {
            const bool keep = all_masked || (m[i] == 0);
            e[i] = keep ? __expf(v[i] - mx) : 0.f;
            sum += e[i];
        }
#pragma unroll
        for (int s = 32; s > 0; s >>= 1) sum += __shfl_xor(sum, s, 64);

        const float inv = 1.f / sum;
        // positions: half i covers cols i*256 + 4*lane + {0..3}
        unsigned* pr = (unsigned*)Ps + 261 * row + 2 * lane;
        pr[0]   = pk2bf(e[0] * inv, e[1] * inv);
        pr[1]   = pk2bf(e[2] * inv, e[3] * inv);
        pr[128] = pk2bf(e[4] * inv, e[5] * inv);
        pr[129] = pk2bf(e[6] * inv, e[7] * inv);
    }

    __syncthreads();

    // --- PV ---
    const int mt  = w >> 1;
    const int n0w = (w & 1) * 32;
    const ushort_t* vb = Vt + (size_t)bh * 64 * 512;

    f32x4 acc[2] = {};
#pragma unroll 4
    for (int ks = 0; ks < 16; ++ks) {
        union { unsigned u[4]; bf16x8 v; } ta;
        const ushort_t* pp = Ps + (size_t)(mt * 16 + sl) * 522 + ks * 32 + quad * 8;
        ta.u[0] = *(const unsigned*)(pp);
        ta.u[1] = *(const unsigned*)(pp + 2);
        ta.u[2] = *(const unsigned*)(pp + 4);
        ta.u[3] = *(const unsigned*)(pp + 6);
        bf16x8 bv[2];
#pragma unroll
        for (int cn = 0; cn < 2; ++cn)
            bv[cn] = *(const bf16x8*)(vb + (size_t)(n0w + cn * 16 + sl) * 512 + ks * 32 + quad * 8);
#pragma unroll
        for (int cn = 0; cn < 2; ++cn)
            acc[cn] = __builtin_amdgcn_mfma_f32_16x16x32_bf16(ta.v, bv[cn], acc[cn], 0, 0, 0);
    }

    const int bidx = bh >> 3, h = bh & 7;
    ushort_t* Cb = Aout + (size_t)bidx * 512 * 512 + h * 64;
#pragma unroll
    for (int cn = 0; cn < 2; ++cn) {
        const int n = n0w + cn * 16 + sl;
#pragma unroll
        for (int reg = 0; reg < 4; ++reg) {
            const int m = r0 + mt * 16 + quad * 4 + reg;
            Cb[(size_t)m * 512 + n] = f2bf(acc[cn][reg]);
        }
    }
}

// ---------------------------------------------------------------------------
extern "C" void kernel_launch(void* const* d_in, const int* in_sizes, int n_in,
                              void* d_out, int out_size, void* d_ws, size_t ws_size,
                              hipStream_t stream) {
    const float* row_emb = (const float*)d_in[0];
    const float* col_emb = (const float*)d_in[1];
    const float* cost    = (const float*)d_in[2];
    const int*   mask    = (const int*)d_in[3];
    const float* Wq      = (const float*)d_in[4];
    const float* Wk      = (const float*)d_in[5];
    const float* Wv      = (const float*)d_in[6];
    const float* Wmix1   = (const float*)d_in[7];
    const float* Wmix2   = (const float*)d_in[8];
    const float* Wout    = (const float*)d_in[9];
    float* out = (float*)d_out;

    char* ws = (char*)d_ws;
    const size_t MB = (size_t)1 << 20;
    ushort_t* convDst = (ushort_t*)ws;
    ushort_t* rowb  = (ushort_t*)(ws);
    ushort_t* colb  = (ushort_t*)(ws + 2 * MB);
    ushort_t* Wqb   = (ushort_t*)(ws + 4 * MB);
    ushort_t* Wkb   = (ushort_t*)(ws + 4 * MB + 512 * 1024);
    ushort_t* Wvb   = (ushort_t*)(ws + 5 * MB);
    ushort_t* Woutb = (ushort_t*)(ws + 5 * MB + 512 * 1024);
    ushort_t* Qb    = (ushort_t*)(ws + 6 * MB);   // bf16 [b*512+r][512]
    ushort_t* Kb    = (ushort_t*)(ws + 8 * MB);
    ushort_t* Vt    = (ushort_t*)(ws + 10 * MB);  // bf16 [bh][d][c]
    ushort_t* Aoutb = (ushort_t*)(ws + 12 * MB);  // bf16 [b*512+r][512]
    float* logitsBuf = (float*)(ws + 40 * MB);    // fp32 [bh][r][c] 33.6 MB

    convert_all<<<3072, 256, 0, stream>>>(row_emb, col_emb, Wq, Wk, Wv, Wout, convDst);

    gemm_qkv<<<dim3(32, 8, 3), 256, 0, stream>>>(rowb, colb, Wqb, Wkb, Wvb, Qb, Kb, Vt);

    dot_mlp_v6<<<dim3(32, 16, 4), 256, 0, stream>>>(Qb, Kb, cost, Wmix1, Wmix2, logitsBuf);

    softmax_pv<<<dim3(16, 32), 256, 0, stream>>>(logitsBuf, mask, Vt, Aoutb);

    gemm_out<<<dim3(32, 8), 256, 0, stream>>>(Aoutb, Woutb, out);
}

// Round 3
// 177.810 us; speedup vs baseline: 1.0396x; 1.0396x over previous
//
#include <hip/hip_runtime.h>
#include <math.h>

typedef __attribute__((ext_vector_type(8))) short bf16x8;
typedef __attribute__((ext_vector_type(4))) float f32x4;
typedef unsigned short ushort_t;

static __device__ inline unsigned short f2bf(float f) {
    union { float f; unsigned u; } v; v.f = f;
    unsigned r = v.u + 0x7fff + ((v.u >> 16) & 1);
    return (unsigned short)(r >> 16);
}

// gfx950 has no cvt_pk_bf16 builtin (learn_hip m240) -- the HW instruction
// exists; use inline asm (non-volatile: pure function, schedulable/CSE-able).
static __device__ inline unsigned pk2bf(float a, float b) {
    unsigned r;
    asm("v_cvt_pk_bf16_f32 %0, %1, %2" : "=v"(r) : "v"(a), "v"(b));
    return r;
}

// ---------------------------------------------------------------------------
// fp32 -> bf16 pre-convert (row_emb, col_emb, Wq, Wk, Wv, Wout) -> ws bf16.
// ---------------------------------------------------------------------------
__global__ __launch_bounds__(256) void convert_all(const float* __restrict__ a0,
                                                   const float* __restrict__ a1,
                                                   const float* __restrict__ a2,
                                                   const float* __restrict__ a3,
                                                   const float* __restrict__ a4,
                                                   const float* __restrict__ a5,
                                                   ushort_t* __restrict__ dst) {
    const size_t e = ((size_t)blockIdx.x * 256 + threadIdx.x) * 4;
    const float* src; size_t off;
    if      (e < 1048576) { src = a0; off = 0; }
    else if (e < 2097152) { src = a1; off = 1048576; }
    else if (e < 2359296) { src = a2; off = 2097152; }
    else if (e < 2621440) { src = a3; off = 2359296; }
    else if (e < 2883584) { src = a4; off = 2621440; }
    else                  { src = a5; off = 2883584; }
    const float4 v = *(const float4*)(src + (e - off));
    uint2 o; o.x = pk2bf(v.x, v.y); o.y = pk2bf(v.z, v.w);
    *(uint2*)(dst + e) = o;
}

// ---------------------------------------------------------------------------
// Q/K/V projections in one launch. z=0: Q=rowb@Wq^T (bf16 rows out);
// z=1: K=colb@Wk^T; z=2: V=colb@Wv^T stored transposed Vt[bh][d][c].
// ---------------------------------------------------------------------------
__global__ __launch_bounds__(256) void gemm_qkv(const ushort_t* __restrict__ rowb,
                                                const ushort_t* __restrict__ colb,
                                                const ushort_t* __restrict__ Wqb,
                                                const ushort_t* __restrict__ Wkb,
                                                const ushort_t* __restrict__ Wvb,
                                                ushort_t* __restrict__ Qb,
                                                ushort_t* __restrict__ Kb,
                                                ushort_t* __restrict__ Vt) {
    const int z = blockIdx.z;
    const ushort_t* A = (z == 0) ? rowb : colb;
    const ushort_t* B = (z == 0) ? Wqb : (z == 1) ? Wkb : Wvb;

    const int t    = threadIdx.x;
    const int w    = t >> 6;
    const int lane = t & 63;
    const int quad = lane >> 4;
    const int sl   = lane & 15;
    const int m0 = blockIdx.x * 64 + (w >> 1) * 32;
    const int n0 = blockIdx.y * 64 + (w & 1) * 32;

    f32x4 acc[2][2] = {};

    for (int k0 = 0; k0 < 512; k0 += 32) {
        bf16x8 a[2], b[2];
#pragma unroll
        for (int rs = 0; rs < 2; ++rs)
            a[rs] = *(const bf16x8*)(A + (size_t)(m0 + rs * 16 + sl) * 512 + k0 + quad * 8);
#pragma unroll
        for (int cs = 0; cs < 2; ++cs)
            b[cs] = *(const bf16x8*)(B + (size_t)(n0 + cs * 16 + sl) * 512 + k0 + quad * 8);
#pragma unroll
        for (int rs = 0; rs < 2; ++rs)
#pragma unroll
            for (int cs = 0; cs < 2; ++cs)
                acc[rs][cs] = __builtin_amdgcn_mfma_f32_16x16x32_bf16(a[rs], b[cs], acc[rs][cs], 0, 0, 0);
    }

#pragma unroll
    for (int rs = 0; rs < 2; ++rs)
#pragma unroll
        for (int cs = 0; cs < 2; ++cs) {
            const int n = n0 + cs * 16 + sl;
            if (z == 2) {
                const int mb   = m0 + rs * 16 + quad * 4;
                const int bidx = mb >> 9, c = mb & 511;
                const int h = n >> 6, d = n & 63;
                uint2 o;
                o.x = pk2bf(acc[rs][cs][0], acc[rs][cs][1]);
                o.y = pk2bf(acc[rs][cs][2], acc[rs][cs][3]);
                *(uint2*)(Vt + (size_t)(((bidx * 8 + h) * 64 + d)) * 512 + c) = o;
            } else {
                ushort_t* C = (z == 0) ? Qb : Kb;
#pragma unroll
                for (int reg = 0; reg < 4; ++reg) {
                    const int m = m0 + rs * 16 + quad * 4 + reg;
                    C[(size_t)m * 512 + n] = f2bf(acc[rs][cs][reg]);
                }
            }
        }
}

// ---------------------------------------------------------------------------
// Final GEMM: out[M][512] = Aoutb @ Woutb^T, fp32 out.
// ---------------------------------------------------------------------------
__global__ __launch_bounds__(256) void gemm_out(const ushort_t* __restrict__ A,
                                                const ushort_t* __restrict__ B,
                                                float* __restrict__ C) {
    const int t    = threadIdx.x;
    const int w    = t >> 6;
    const int lane = t & 63;
    const int quad = lane >> 4;
    const int sl   = lane & 15;
    const int m0 = blockIdx.x * 64 + (w >> 1) * 32;
    const int n0 = blockIdx.y * 64 + (w & 1) * 32;

    f32x4 acc[2][2] = {};

    for (int k0 = 0; k0 < 512; k0 += 32) {
        bf16x8 a[2], b[2];
#pragma unroll
        for (int rs = 0; rs < 2; ++rs)
            a[rs] = *(const bf16x8*)(A + (size_t)(m0 + rs * 16 + sl) * 512 + k0 + quad * 8);
#pragma unroll
        for (int cs = 0; cs < 2; ++cs)
            b[cs] = *(const bf16x8*)(B + (size_t)(n0 + cs * 16 + sl) * 512 + k0 + quad * 8);
#pragma unroll
        for (int rs = 0; rs < 2; ++rs)
#pragma unroll
            for (int cs = 0; cs < 2; ++cs)
                acc[rs][cs] = __builtin_amdgcn_mfma_f32_16x16x32_bf16(a[rs], b[cs], acc[rs][cs], 0, 0, 0);
    }

#pragma unroll
    for (int rs = 0; rs < 2; ++rs)
#pragma unroll
        for (int cs = 0; cs < 2; ++cs) {
            const int n = n0 + cs * 16 + sl;
#pragma unroll
            for (int reg = 0; reg < 4; ++reg) {
                const int m = m0 + rs * 16 + quad * 4 + reg;
                C[(size_t)m * 512 + n] = acc[rs][cs][reg];
            }
        }
}

// ---------------------------------------------------------------------------
// dot + mixing MLP v7: identical structure to v6 (256 thr, 32x16 tile,
// grid (32,16,4)); single change vs v6: pk2bf is now one HW instruction
// (v_cvt_pk_bf16_f32) instead of a ~10-op bit-twiddle fallback.
// ---------------------------------------------------------------------------
__global__ __launch_bounds__(256) void dot_mlp_v7(const ushort_t* __restrict__ Qb,
                                                  const ushort_t* __restrict__ Kb,
                                                  const float* __restrict__ cost,
                                                  const float* __restrict__ W1,
                                                  const float* __restrict__ W2,
                                                  float* __restrict__ logits) {
    __shared__ ushort_t Xs[512 * 20];       // 20 KB, row stride 20 shorts
    __shared__ ushort_t W1fs[128 * 16];     // 4 KB
    __shared__ ushort_t W2ss[8 * 128];      // 2 KB

    const int b  = blockIdx.z;
    const int r0 = blockIdx.y * 32;
    const int c0 = blockIdx.x * 16;
    const int t    = threadIdx.x;
    const int w    = t >> 6;
    const int lane = t & 63;
    const int quad = lane >> 4;
    const int sl   = lane & 15;

    const bf16x8 zf = {0, 0, 0, 0, 0, 0, 0, 0};

    // --- stage weights ---
    if (t < 128) {
        float s = 0.f;
#pragma unroll
        for (int h = 0; h < 8; ++h) {
            W1fs[t * 16 + h] = f2bf(W1[t * 16 + 2 * h]);
            s += W1[t * 16 + 2 * h + 1];
        }
        W1fs[t * 16 + 8] = f2bf(s);
#pragma unroll
        for (int k = 9; k < 16; ++k) W1fs[t * 16 + k] = 0;
    }
#pragma unroll
    for (int i = 0; i < 4; ++i) W2ss[t + i * 256] = f2bf(W2[t + i * 256]);

    // --- cost -> X slot 8 (dword 4); zero dwords 5..7 ---
#pragma unroll
    for (int i = 0; i < 2; ++i) {
        const int cell = t + i * 256;
        const int rl = cell >> 4, cl = cell & 15;
        unsigned* base = (unsigned*)(Xs + cell * 20) + 4;
        base[0] = (unsigned)f2bf(cost[((size_t)b * 512 + r0 + rl) * 512 + c0 + cl]);
        base[1] = 0; base[2] = 0; base[3] = 0;
    }

    // --- Phase A: wave = (row-half rs, head-quad hbj) ---
    {
        const int rs  = w >> 1;
        const int hbj = w & 1;
        unsigned uu[2][4];
#pragma unroll
        for (int hp = 0; hp < 2; ++hp) {
            const int h0 = hbj * 4 + hp * 2;
            bf16x8 qa[2][2], ka[2][2];
#pragma unroll
            for (int hh = 0; hh < 2; ++hh)
#pragma unroll
                for (int ks = 0; ks < 2; ++ks) {
                    qa[hh][ks] = *(const bf16x8*)(Qb +
                        ((size_t)(b * 512 + r0 + rs * 16 + sl) * 512 + (h0 + hh) * 64 + ks * 32 + quad * 8));
                    ka[hh][ks] = *(const bf16x8*)(Kb +
                        ((size_t)(b * 512 + c0 + sl) * 512 + (h0 + hh) * 64 + ks * 32 + quad * 8));
                }
            f32x4 ac0 = {0.f, 0.f, 0.f, 0.f}, ac1 = {0.f, 0.f, 0.f, 0.f};
            ac0 = __builtin_amdgcn_mfma_f32_16x16x32_bf16(qa[0][0], ka[0][0], ac0, 0, 0, 0);
            ac0 = __builtin_amdgcn_mfma_f32_16x16x32_bf16(qa[0][1], ka[0][1], ac0, 0, 0, 0);
            ac1 = __builtin_amdgcn_mfma_f32_16x16x32_bf16(qa[1][0], ka[1][0], ac1, 0, 0, 0);
            ac1 = __builtin_amdgcn_mfma_f32_16x16x32_bf16(qa[1][1], ka[1][1], ac1, 0, 0, 0);
#pragma unroll
            for (int reg = 0; reg < 4; ++reg)
                uu[hp][reg] = pk2bf(ac0[reg] * 0.125f, ac1[reg] * 0.125f);
        }
        const int rowb = rs * 16 + quad * 4;
#pragma unroll
        for (int reg = 0; reg < 4; ++reg) {
            const int cell = (rowb + reg) * 16 + sl;
            unsigned* xp = (unsigned*)(Xs + cell * 20) + hbj * 2;
            xp[0] = uu[0][reg];   // heads hbj*4+0, hbj*4+1
            xp[1] = uu[1][reg];   // heads hbj*4+2, hbj*4+3
        }
    }

    __syncthreads();

    // --- Phase B ---
    // W1 A-frags: lane holds W1row = nt*16+sl, k = quad*8+i (k>=16 zero-padded).
    bf16x8 aw1[8];
#pragma unroll
    for (int nt = 0; nt < 8; ++nt)
        aw1[nt] = (quad < 2) ? *(const bf16x8*)&W1fs[(nt * 16 + sl) * 16 + quad * 8] : zf;

    // W2 A-frags with k permuted to match the hidT pack layout:
    // frag ks, elem i  <->  hidden j = (2ks + (i>>2))*16 + quad*4 + (i&3)
    bf16x8 w2f[4];
#pragma unroll
    for (int ks = 0; ks < 4; ++ks) {
        union { ushort_t s[8]; bf16x8 v; } tu;
#pragma unroll
        for (int i = 0; i < 8; ++i) {
            const int j = (2 * ks + (i >> 2)) * 16 + quad * 4 + (i & 3);
            tu.s[i] = (sl < 8) ? W2ss[sl * 128 + j] : (ushort_t)0;
        }
        w2f[ks] = tu.v;
    }

#pragma unroll
    for (int mt = 0; mt < 8; ++mt) {
        const int gmt  = w * 8 + mt;       // row within tile, 0..31
        const int cell = gmt * 16 + sl;

        // X B-frag: lane holds cell, k = quad*8+i (k>=16 zero-padded).
        bf16x8 a1 = zf;
        if (quad < 2) {
            const unsigned* xr = (const unsigned*)Xs + (size_t)cell * 10 + quad * 4;
            union { unsigned u[4]; bf16x8 v; } tmp;
            tmp.u[0] = xr[0]; tmp.u[1] = xr[1]; tmp.u[2] = xr[2]; tmp.u[3] = xr[3];
            a1 = tmp.v;
        }

        // layer 1: hidT -> lane holds hid units (quad*4+reg) for cell = sl.
        f32x4 acc2 = {0.f, 0.f, 0.f, 0.f};
#pragma unroll
        for (int ks = 0; ks < 4; ++ks) {
            f32x4 z = {0.f, 0.f, 0.f, 0.f};
            const f32x4 h0v = __builtin_amdgcn_mfma_f32_16x16x32_bf16(aw1[2 * ks],     a1, z, 0, 0, 0);
            const f32x4 h1v = __builtin_amdgcn_mfma_f32_16x16x32_bf16(aw1[2 * ks + 1], a1, z, 0, 0, 0);
            union { unsigned u[4]; bf16x8 v; } hb;
            hb.u[0] = pk2bf(fmaxf(h0v[0], 0.f), fmaxf(h0v[1], 0.f));
            hb.u[1] = pk2bf(fmaxf(h0v[2], 0.f), fmaxf(h0v[3], 0.f));
            hb.u[2] = pk2bf(fmaxf(h1v[0], 0.f), fmaxf(h1v[1], 0.f));
            hb.u[3] = pk2bf(fmaxf(h1v[2], 0.f), fmaxf(h1v[3], 0.f));
            acc2 = __builtin_amdgcn_mfma_f32_16x16x32_bf16(w2f[ks], hb.v, acc2, 0, 0, 0);
        }

        // msT: row (quad*4+reg) = head (valid quad<2), col (sl) = cell.
        if (quad < 2) {
            const int r = r0 + gmt;
            const int c = c0 + sl;
#pragma unroll
            for (int reg = 0; reg < 4; ++reg) {
                const int h = quad * 4 + reg;
                logits[((size_t)(b * 8 + h) * 512 + r) * 512 + c] = acc2[reg];
            }
        }
    }
}

// ---------------------------------------------------------------------------
// Fused masked-softmax + PV. grid (16 r-tiles, 32 bh), 256 threads (4 waves).
// Ps row stride 522 shorts (odd dword stride 261) -> ~2-way bank conflicts.
// ---------------------------------------------------------------------------
__global__ __launch_bounds__(256) void softmax_pv(const float* __restrict__ logits,
                                                  const int* __restrict__ mask,
                                                  const ushort_t* __restrict__ Vt,
                                                  ushort_t* __restrict__ Aout) {
    __shared__ ushort_t Ps[32 * 522];   // 33.4 KB

    const int t    = threadIdx.x;
    const int w    = t >> 6;
    const int lane = t & 63;
    const int quad = lane >> 4;
    const int sl   = lane & 15;
    const int rt = blockIdx.x;
    const int bh = blockIdx.y;
    const int r0 = rt * 32;

    // --- softmax: 8 rows per wave, vectorized float4/int4 loads ---
#pragma unroll
    for (int rr = 0; rr < 8; ++rr) {
        const int row = w * 8 + rr;
        const float* lp = logits + ((size_t)bh * 512 + r0 + row) * 512;
        const int*   mp = mask   + ((size_t)bh * 512 + r0 + row) * 512;

        const float4 f0 = ((const float4*)lp)[lane];
        const float4 f1 = ((const float4*)lp)[lane + 64];
        const int4   m0 = ((const int4*)mp)[lane];
        const int4   m1 = ((const int4*)mp)[lane + 64];

        float v[8]; int m[8];
        v[0] = f0.x; v[1] = f0.y; v[2] = f0.z; v[3] = f0.w;
        v[4] = f1.x; v[5] = f1.y; v[6] = f1.z; v[7] = f1.w;
        m[0] = m0.x; m[1] = m0.y; m[2] = m0.z; m[3] = m0.w;
        m[4] = m1.x; m[5] = m1.y; m[6] = m1.z; m[7] = m1.w;

        int allm = 1;
#pragma unroll
        for (int i = 0; i < 8; ++i) allm &= (m[i] != 0);
        const bool all_masked = (__all(allm) != 0);

        float mx = -__builtin_inff();
#pragma unroll
        for (int i = 0; i < 8; ++i) {
            const bool keep = all_masked || (m[i] == 0);
            if (keep) mx = fmaxf(mx, v[i]);
        }
#pragma unroll
        for (int s = 32; s > 0; s >>= 1) mx = fmaxf(mx, __shfl_xor(mx, s, 64));

        float e[8]; float sum = 0.f;
#pragma unroll
        for (int i = 0; i < 8; ++i) {
            const bool keep = all_masked || (m[i] == 0);
            e[i] = keep ? __expf(v[i] - mx) : 0.f;
            sum += e[i];
        }
#pragma unroll
        for (int s = 32; s > 0; s >>= 1) sum += __shfl_xor(sum, s, 64);

        const float inv = 1.f / sum;
        // positions: half i covers cols i*256 + 4*lane + {0..3}
        unsigned* pr = (unsigned*)Ps + 261 * row + 2 * lane;
        pr[0]   = pk2bf(e[0] * inv, e[1] * inv);
        pr[1]   = pk2bf(e[2] * inv, e[3] * inv);
        pr[128] = pk2bf(e[4] * inv, e[5] * inv);
        pr[129] = pk2bf(e[6] * inv, e[7] * inv);
    }

    __syncthreads();

    // --- PV ---
    const int mt  = w >> 1;
    const int n0w = (w & 1) * 32;
    const ushort_t* vb = Vt + (size_t)bh * 64 * 512;

    f32x4 acc[2] = {};
#pragma unroll 4
    for (int ks = 0; ks < 16; ++ks) {
        union { unsigned u[4]; bf16x8 v; } ta;
        const ushort_t* pp = Ps + (size_t)(mt * 16 + sl) * 522 + ks * 32 + quad * 8;
        ta.u[0] = *(const unsigned*)(pp);
        ta.u[1] = *(const unsigned*)(pp + 2);
        ta.u[2] = *(const unsigned*)(pp + 4);
        ta.u[3] = *(const unsigned*)(pp + 6);
        bf16x8 bv[2];
#pragma unroll
        for (int cn = 0; cn < 2; ++cn)
            bv[cn] = *(const bf16x8*)(vb + (size_t)(n0w + cn * 16 + sl) * 512 + ks * 32 + quad * 8);
#pragma unroll
        for (int cn = 0; cn < 2; ++cn)
            acc[cn] = __builtin_amdgcn_mfma_f32_16x16x32_bf16(ta.v, bv[cn], acc[cn], 0, 0, 0);
    }

    const int bidx = bh >> 3, h = bh & 7;
    ushort_t* Cb = Aout + (size_t)bidx * 512 * 512 + h * 64;
#pragma unroll
    for (int cn = 0; cn < 2; ++cn) {
        const int n = n0w + cn * 16 + sl;
#pragma unroll
        for (int reg = 0; reg < 4; ++reg) {
            const int m = r0 + mt * 16 + quad * 4 + reg;
            Cb[(size_t)m * 512 + n] = f2bf(acc[cn][reg]);
        }
    }
}

// ---------------------------------------------------------------------------
extern "C" void kernel_launch(void* const* d_in, const int* in_sizes, int n_in,
                              void* d_out, int out_size, void* d_ws, size_t ws_size,
                              hipStream_t stream) {
    const float* row_emb = (const float*)d_in[0];
    const float* col_emb = (const float*)d_in[1];
    const float* cost    = (const float*)d_in[2];
    const int*   mask    = (const int*)d_in[3];
    const float* Wq      = (const float*)d_in[4];
    const float* Wk      = (const float*)d_in[5];
    const float* Wv      = (const float*)d_in[6];
    const float* Wmix1   = (const float*)d_in[7];
    const float* Wmix2   = (const float*)d_in[8];
    const float* Wout    = (const float*)d_in[9];
    float* out = (float*)d_out;

    char* ws = (char*)d_ws;
    const size_t MB = (size_t)1 << 20;
    ushort_t* convDst = (ushort_t*)ws;
    ushort_t* rowb  = (ushort_t*)(ws);
    ushort_t* colb  = (ushort_t*)(ws + 2 * MB);
    ushort_t* Wqb   = (ushort_t*)(ws + 4 * MB);
    ushort_t* Wkb   = (ushort_t*)(ws + 4 * MB + 512 * 1024);
    ushort_t* Wvb   = (ushort_t*)(ws + 5 * MB);
    ushort_t* Woutb = (ushort_t*)(ws + 5 * MB + 512 * 1024);
    ushort_t* Qb    = (ushort_t*)(ws + 6 * MB);   // bf16 [b*512+r][512]
    ushort_t* Kb    = (ushort_t*)(ws + 8 * MB);
    ushort_t* Vt    = (ushort_t*)(ws + 10 * MB);  // bf16 [bh][d][c]
    ushort_t* Aoutb = (ushort_t*)(ws + 12 * MB);  // bf16 [b*512+r][512]
    float* logitsBuf = (float*)(ws + 40 * MB);    // fp32 [bh][r][c] 33.6 MB

    convert_all<<<3072, 256, 0, stream>>>(row_emb, col_emb, Wq, Wk, Wv, Wout, convDst);

    gemm_qkv<<<dim3(32, 8, 3), 256, 0, stream>>>(rowb, colb, Wqb, Wkb, Wvb, Qb, Kb, Vt);

    dot_mlp_v7<<<dim3(32, 16, 4), 256, 0, stream>>>(Qb, Kb, cost, Wmix1, Wmix2, logitsBuf);

    softmax_pv<<<dim3(16, 32), 256, 0, stream>>>(logitsBuf, mask, Vt, Aoutb);

    gemm_out<<<dim3(32, 8), 256, 0, stream>>>(Aoutb, Woutb, out);
}